// Round 3
// baseline (339.750 us; speedup 1.0000x reference)
//
#include <hip/hip_runtime.h>
#include <hip/hip_cooperative_groups.h>

namespace cg = cooperative_groups;

// Problem constants (fixed by the reference file)
#define BATCH 2048
#define MM    256
#define DD    1024

// Main-kernel tiling
#define BB 128          // batches per block
#define BM 64           // mixture components per block
#define KC 16           // d per LDS stage
#define TB 8            // per-thread batch tile
#define TM 4            // per-thread m tile
#define LXS (BB + 4)    // padded LDS row stride (words) — conflict-free frag reads
#define LRS (BM + 4)
#define NBT (BATCH / BB)   // 16 b-tiles
#define SD16 16
#define DC16 (DD / SD16)   // 64 d per main tile in the fused path

#define LOG2E 1.4426950408889634f
#define LN2   0.6931471805599453f

// ---- exact log2 bookkeeping via frexp (full-rate VALU, no transcendental) ----
__device__ __forceinline__ float fr_mant(float x) {
#if __has_builtin(__builtin_amdgcn_frexp_mantf)
    return __builtin_amdgcn_frexp_mantf(x);
#else
    unsigned u = __float_as_uint(x);
    return __uint_as_float((u & 0x807FFFFFu) | 0x3F000000u);
#endif
}
__device__ __forceinline__ int fr_exp(float x) {
#if __has_builtin(__builtin_amdgcn_frexp_expf)
    return __builtin_amdgcn_frexp_expf(x);
#else
    return (int)((__float_as_uint(x) >> 23) & 0xFFu) - 126;
#endif
}

// ===========================================================================
// Phase bodies as inline functions so the fused cooperative kernel and the
// standalone (fallback) kernels share EXACTLY the same verified code.
// ===========================================================================

// ---- Phase A: r[m][d] = e^z - 1 ; cst[m] = sum_d log2 q + log2 softmax(W) --
__device__ __forceinline__ void precomp_body(
        const float* __restrict__ P, const float* __restrict__ Wv,
        float* __restrict__ rbuf, float* __restrict__ cst,
        int m, int t, float* smA, float* smB) {
    const int lane = t & 63, wid = t >> 6;

    float4 z = ((const float4*)(P + (size_t)m * DD))[t];
    float e0 = __expf(z.x), e1 = __expf(z.y), e2 = __expf(z.z), e3 = __expf(z.w);
    ((float4*)(rbuf + (size_t)m * DD))[t] =
        make_float4(e0 - 1.f, e1 - 1.f, e2 - 1.f, e3 - 1.f);
    float part = -(__log2f(1.f + e0) + __log2f(1.f + e1) +
                   __log2f(1.f + e2) + __log2f(1.f + e3));

    #pragma unroll
    for (int o = 32; o; o >>= 1) part += __shfl_xor(part, o);
    if (lane == 0) smA[wid] = part;

    float w = Wv[t];
    float mx = w;
    #pragma unroll
    for (int o = 32; o; o >>= 1) mx = fmaxf(mx, __shfl_xor(mx, o));
    if (lane == 0) smB[wid] = mx;
    __syncthreads();

    float rowc = smA[0] + smA[1] + smA[2] + smA[3];
    float gmx  = fmaxf(fmaxf(smB[0], smB[1]), fmaxf(smB[2], smB[3]));

    float se = __expf(w - gmx);
    #pragma unroll
    for (int o = 32; o; o >>= 1) se += __shfl_xor(se, o);
    __syncthreads();
    if (lane == 0) smA[wid] = se;
    __syncthreads();

    if (t == 0) {
        float sum = smA[0] + smA[1] + smA[2] + smA[3];
        cst[m] = rowc + (Wv[m] - gmx) * LOG2E - __log2f(sum);
    }
}

// ---- Phase B: pbuf[d_id][b][m] = sum_{d in split} log2(1 + x[b][d]*r[m][d])
// Register-prefetch pipelined staging; XCD-swizzled decode (4 consecutive k
// on one XCD share the (b,d) x-tile -> L2 reuse). Exponent extraction once
// per 16-d stage: t = 1+x*r in [~0.008, ~110] -> 16-product in [1e-33, 5e32],
// inside fp32 normal range.
__device__ __forceinline__ void main_body(
        const float* __restrict__ x, const float* __restrict__ rbuf,
        float* __restrict__ pbuf, int dc, int gid, int tid,
        float* lx, float* lr) {
    const int tx = tid & 15;    // m direction (16 * TM = 64)
    const int ty = tid >> 4;    // batch direction (16 * TB = 128)

    const int xcd  = gid & 7;
    const int k    = gid >> 3;
    const int m_id = k & 3;
    const int tile = (k >> 2) * 8 + xcd;
    const int b_id = tile & (NBT - 1);
    const int d_id = tile / NBT;

    const int m0 = m_id * BM;
    const int b0 = b_id * BB;
    const int d0 = d_id * dc;
    const int NC = dc / KC;

    const int rowx = tid >> 2, segx = tid & 3;
    const float* xp0 = x + (size_t)(b0 + rowx) * DD + d0 + segx * 4;
    const float* xp1 = xp0 + (size_t)64 * DD;
    const float* rp  = rbuf + (size_t)(m0 + rowx) * DD + d0 + segx * 4;

    float4 cx0 = *(const float4*)xp0;
    float4 cx1 = *(const float4*)xp1;
    float4 cr  = *(const float4*)rp;

    float prod[TB][TM];
    int   acce[TB][TM];
    #pragma unroll
    for (int i = 0; i < TB; ++i)
        #pragma unroll
        for (int j = 0; j < TM; ++j) { prod[i][j] = 1.0f; acce[i][j] = 0; }

    for (int c = 0; c < NC; ++c) {
        __syncthreads();
        {
            const int base = segx * 4;
            lx[(base + 0) * LXS + rowx] = cx0.x;
            lx[(base + 1) * LXS + rowx] = cx0.y;
            lx[(base + 2) * LXS + rowx] = cx0.z;
            lx[(base + 3) * LXS + rowx] = cx0.w;
            lx[(base + 0) * LXS + rowx + 64] = cx1.x;
            lx[(base + 1) * LXS + rowx + 64] = cx1.y;
            lx[(base + 2) * LXS + rowx + 64] = cx1.z;
            lx[(base + 3) * LXS + rowx + 64] = cx1.w;
            if (rowx < BM) {
                lr[(base + 0) * LRS + rowx] = cr.x;
                lr[(base + 1) * LRS + rowx] = cr.y;
                lr[(base + 2) * LRS + rowx] = cr.z;
                lr[(base + 3) * LRS + rowx] = cr.w;
            }
        }
        if (c + 1 < NC) {
            xp0 += KC; xp1 += KC; rp += KC;
            cx0 = *(const float4*)xp0;
            cx1 = *(const float4*)xp1;
            cr  = *(const float4*)rp;
        }
        __syncthreads();

        #pragma unroll
        for (int kc = 0; kc < KC; ++kc) {
            const float4* xp = (const float4*)&lx[kc * LXS + TB * ty];
            float4 xa = xp[0], xb = xp[1];
            const float4* rpf = (const float4*)&lr[kc * LRS + TM * tx];
            float4 rv = rpf[0];
            float xf[TB] = {xa.x, xa.y, xa.z, xa.w, xb.x, xb.y, xb.z, xb.w};
            float rf[TM] = {rv.x, rv.y, rv.z, rv.w};
            #pragma unroll
            for (int i = 0; i < TB; ++i)
                #pragma unroll
                for (int j = 0; j < TM; ++j)
                    prod[i][j] *= fmaf(xf[i], rf[j], 1.0f);
        }
        #pragma unroll
        for (int i = 0; i < TB; ++i)
            #pragma unroll
            for (int j = 0; j < TM; ++j) {
                float p = prod[i][j];
                acce[i][j] += fr_exp(p);
                prod[i][j] = fr_mant(p);
            }
    }

    float* pb = pbuf + ((size_t)d_id * BATCH + b0) * MM + m0;
    #pragma unroll
    for (int i = 0; i < TB; ++i) {
        float4 vv;
        vv.x = (float)acce[i][0] + __log2f(prod[i][0]);
        vv.y = (float)acce[i][1] + __log2f(prod[i][1]);
        vv.z = (float)acce[i][2] + __log2f(prod[i][2]);
        vv.w = (float)acce[i][3] + __log2f(prod[i][3]);
        *(float4*)&pb[(size_t)(TB * ty + i) * MM + TM * tx] = vv;
    }
}

// ---- Phase C: one wave per batch; lane covers 4 m's (float4); 16 partials --
__device__ __forceinline__ void finalize16_body(
        const float4* __restrict__ pbuf4, const float4* __restrict__ cst4,
        float* __restrict__ out, int b, int lane) {
    float4 v = cst4[lane];
    const float4* pb = pbuf4 + (size_t)b * (MM / 4) + lane;
    #pragma unroll
    for (int s = 0; s < 16; ++s) {
        float4 t = pb[(size_t)s * BATCH * (MM / 4)];
        v.x += t.x; v.y += t.y; v.z += t.z; v.w += t.w;
    }

    float mx = fmaxf(fmaxf(v.x, v.y), fmaxf(v.z, v.w));
    #pragma unroll
    for (int o = 32; o; o >>= 1) mx = fmaxf(mx, __shfl_xor(mx, o));

    float s = exp2f(v.x - mx) + exp2f(v.y - mx) + exp2f(v.z - mx) + exp2f(v.w - mx);
    #pragma unroll
    for (int o = 32; o; o >>= 1) s += __shfl_xor(s, o);

    if (lane == 0) out[b] = LN2 * (mx + __log2f(s));
}

// ===========================================================================
// Fused cooperative kernel: precomp -> grid.sync -> main -> grid.sync -> fin.
// Grid MUST be 1024 blocks (= NBT*16*4); 4 blocks/CU co-resident.
// ===========================================================================
__global__ __launch_bounds__(256, 4) void fused_kernel(
        const float* __restrict__ x, const float* __restrict__ Wv,
        const float* __restrict__ P, float* __restrict__ rbuf,
        float* __restrict__ cst, float* __restrict__ pbuf,
        float* __restrict__ out) {
    __shared__ __align__(16) float lx[KC * LXS];
    __shared__ __align__(16) float lr[KC * LRS];
    __shared__ float smA[4], smB[4];

    cg::grid_group grid = cg::this_grid();
    const int tid = threadIdx.x;

    // Phase A: blocks 0..MM-1 each handle one mixture row.
    if (blockIdx.x < MM)
        precomp_body(P, Wv, rbuf, cst, blockIdx.x, tid, smA, smB);
    grid.sync();

    // Phase B: all 1024 blocks.
    main_body(x, rbuf, pbuf, DC16, blockIdx.x, tid, lx, lr);
    grid.sync();

    // Phase C: waves 0,1 of each block handle one batch each (8 act. waves/CU,
    // same parallelism as the standalone finalize16 at 2 blocks/CU x 4 waves).
    const int w = tid >> 6;
    if (w < 2)
        finalize16_body((const float4*)pbuf, (const float4*)cst, out,
                        blockIdx.x * 2 + w, tid & 63);
}

// ===========================================================================
// Standalone kernels (fallback path when cooperative launch is unavailable
// or the workspace is too small for sd=16).
// ===========================================================================
__global__ __launch_bounds__(256) void precomp_kernel(
        const float* __restrict__ P, const float* __restrict__ Wv,
        float* __restrict__ rbuf, float* __restrict__ cst) {
    __shared__ float smA[4], smB[4];
    precomp_body(P, Wv, rbuf, cst, blockIdx.x, threadIdx.x, smA, smB);
}

__global__ __launch_bounds__(256, 4) void main_kernel(
        const float* __restrict__ x, const float* __restrict__ rbuf,
        float* __restrict__ pbuf, int dc) {
    __shared__ __align__(16) float lx[KC * LXS];
    __shared__ __align__(16) float lr[KC * LRS];
    main_body(x, rbuf, pbuf, dc, blockIdx.x, threadIdx.x, lx, lr);
}

__global__ __launch_bounds__(256) void finalize16_kernel(
        const float4* __restrict__ pbuf4, const float4* __restrict__ cst4,
        float* __restrict__ out) {
    const int w = threadIdx.x >> 6;
    finalize16_body(pbuf4, cst4, out, blockIdx.x * 4 + w, threadIdx.x & 63);
}

__global__ __launch_bounds__(256) void finalize_kernel(
        const float* __restrict__ pbuf, const float* __restrict__ cst,
        float* __restrict__ out, int sd) {
    const int lane = threadIdx.x & 63;
    const int w = threadIdx.x >> 6;
    const int b = blockIdx.x * 4 + w;

    float v0 = cst[lane];
    float v1 = cst[lane + 64];
    float v2 = cst[lane + 128];
    float v3 = cst[lane + 192];

    for (int s = 0; s < sd; ++s) {
        const float* row = pbuf + ((size_t)s * BATCH + b) * MM;
        v0 += row[lane];
        v1 += row[lane + 64];
        v2 += row[lane + 128];
        v3 += row[lane + 192];
    }

    float mx = fmaxf(fmaxf(v0, v1), fmaxf(v2, v3));
    #pragma unroll
    for (int o = 32; o; o >>= 1) mx = fmaxf(mx, __shfl_xor(mx, o));

    float s = exp2f(v0 - mx) + exp2f(v1 - mx) + exp2f(v2 - mx) + exp2f(v3 - mx);
    #pragma unroll
    for (int o = 32; o; o >>= 1) s += __shfl_xor(s, o);

    if (lane == 0) out[b] = LN2 * (mx + __log2f(s));
}

extern "C" void kernel_launch(void* const* d_in, const int* in_sizes, int n_in,
                              void* d_out, int out_size, void* d_ws, size_t ws_size,
                              hipStream_t stream) {
    const float* x  = (const float*)d_in[0];
    const float* Wv = (const float*)d_in[1];
    const float* P  = (const float*)d_in[2];

    // ws layout (floats): [rbuf: MM*DD][cst: MM][pbuf: sd*BATCH*MM]
    float* ws   = (float*)d_ws;
    float* rbuf = ws;
    float* cst  = rbuf + (size_t)MM * DD;
    float* pbuf = cst + MM;
    float* outp = (float*)d_out;

    size_t fixed = ((size_t)MM * DD + MM) * sizeof(float);
    size_t avail = (ws_size > fixed) ? (ws_size - fixed) : 0;
    int sd = 16;
    while (sd > 1 && (size_t)sd * BATCH * MM * sizeof(float) > avail) sd >>= 1;

    if (sd == 16) {
        // Fused single-dispatch path: 1024 blocks (= NBT*16*4), cooperative.
        void* args[] = {(void*)&x, (void*)&Wv, (void*)&P, (void*)&rbuf,
                        (void*)&cst, (void*)&pbuf, (void*)&outp};
        hipError_t e = hipLaunchCooperativeKernel(
            (const void*)fused_kernel, dim3(NBT * SD16 * 4), dim3(256),
            args, 0, stream);
        if (e == hipSuccess) return;
        (void)hipGetLastError();   // clear, fall through to 3-kernel path
    }

    precomp_kernel<<<MM, 256, 0, stream>>>(P, Wv, rbuf, cst);
    int nblocks = NBT * sd * 4;   // 1-D swizzled grid
    main_kernel<<<nblocks, 256, 0, stream>>>(x, rbuf, pbuf, DD / sd);
    if (sd == 16)
        finalize16_kernel<<<BATCH / 4, 256, 0, stream>>>(
            (const float4*)pbuf, (const float4*)cst, (float*)d_out);
    else
        finalize_kernel<<<BATCH / 4, 256, 0, stream>>>(pbuf, cst, (float*)d_out, sd);
}

// Round 9
// 93.739 us; speedup vs baseline: 3.6244x; 3.6244x over previous
//
#include <hip/hip_runtime.h>

// Problem constants (fixed by the reference file)
#define BATCH 2048
#define MM    256
#define DD    1024

// Main-kernel tiling
#define BB 128          // batches per block
#define BM 64           // mixture components per block
#define KC 16           // d per LDS stage
#define TB 8            // per-thread batch tile
#define TM 4            // per-thread m tile
#define LXS (BB + 4)    // padded LDS row stride (words) — conflict-free frag reads
#define LRS (BM + 4)
#define NBT (BATCH / BB)   // 16 b-tiles

#define LOG2E 1.4426950408889634f
#define LN2   0.6931471805599453f

typedef float v2f __attribute__((ext_vector_type(2)));

// ---- exact log2 bookkeeping via frexp (full-rate VALU, no transcendental) ----
__device__ __forceinline__ float fr_mant(float x) {
#if __has_builtin(__builtin_amdgcn_frexp_mantf)
    return __builtin_amdgcn_frexp_mantf(x);
#else
    unsigned u = __float_as_uint(x);
    return __uint_as_float((u & 0x807FFFFFu) | 0x3F000000u);
#endif
}
__device__ __forceinline__ int fr_exp(float x) {
#if __has_builtin(__builtin_amdgcn_frexp_expf)
    return __builtin_amdgcn_frexp_expf(x);
#else
    return (int)((__float_as_uint(x) >> 23) & 0xFFu) - 126;
#endif
}

// ---------------------------------------------------------------------------
// Kernel A: r[m][d] = e^z - 1  (lik = q*(1 + x*r), q = 1-p)
// cst[m] = sum_d log2 q[m][d] + log2 softmax(W)[m]
// ---------------------------------------------------------------------------
__global__ __launch_bounds__(256) void precomp_kernel(
        const float* __restrict__ P, const float* __restrict__ Wv,
        float* __restrict__ rbuf, float* __restrict__ cst) {
    const int m = blockIdx.x;
    const int t = threadIdx.x;
    const int lane = t & 63, wid = t >> 6;

    float4 z = ((const float4*)(P + (size_t)m * DD))[t];
    float e0 = __expf(z.x), e1 = __expf(z.y), e2 = __expf(z.z), e3 = __expf(z.w);
    ((float4*)(rbuf + (size_t)m * DD))[t] =
        make_float4(e0 - 1.f, e1 - 1.f, e2 - 1.f, e3 - 1.f);
    float part = -(__log2f(1.f + e0) + __log2f(1.f + e1) +
                   __log2f(1.f + e2) + __log2f(1.f + e3));

    __shared__ float smA[4], smB[4];

    #pragma unroll
    for (int o = 32; o; o >>= 1) part += __shfl_xor(part, o);
    if (lane == 0) smA[wid] = part;

    float w = Wv[t];
    float mx = w;
    #pragma unroll
    for (int o = 32; o; o >>= 1) mx = fmaxf(mx, __shfl_xor(mx, o));
    if (lane == 0) smB[wid] = mx;
    __syncthreads();

    float rowc = smA[0] + smA[1] + smA[2] + smA[3];
    float gmx  = fmaxf(fmaxf(smB[0], smB[1]), fmaxf(smB[2], smB[3]));

    float se = __expf(w - gmx);
    #pragma unroll
    for (int o = 32; o; o >>= 1) se += __shfl_xor(se, o);
    __syncthreads();
    if (lane == 0) smA[wid] = se;
    __syncthreads();

    if (t == 0) {
        float sum = smA[0] + smA[1] + smA[2] + smA[3];
        cst[m] = rowc + (Wv[m] - gmx) * LOG2E - __log2f(sum);
    }
}

// ---------------------------------------------------------------------------
// Kernel B: pbuf[d_id][b][m] = sum_{d in split} log2(1 + x[b][d]*r[m][d])
// Register-prefetch pipelined staging; XCD-swizzled 1-D grid so the 4
// m-blocks sharing an x-tile run consecutively on one XCD (L2 reuse).
// Inner loop in packed FP32 (v_pk_fma_f32 / v_pk_mul_f32 via <2 x float>):
// prod pairs run along the batch axis (x frags from the b128 loads are
// already even-aligned VGPR pairs); only the 4 r values are splatted.
// Exponent extraction once per 16-d stage: t = 1+x*r in [~0.008, ~110]
// -> 16-product in [1e-33, 5e32], inside fp32 normal range.
// ---------------------------------------------------------------------------
__global__ __launch_bounds__(256, 4) void main_kernel(
        const float* __restrict__ x, const float* __restrict__ rbuf,
        float* __restrict__ pbuf, int dc) {
    __shared__ __align__(16) float lx[KC * LXS];
    __shared__ __align__(16) float lr[KC * LRS];

    const int tid = threadIdx.x;
    const int tx = tid & 15;    // m direction (16 * TM = 64)
    const int ty = tid >> 4;    // batch direction (16 * TB = 128)

    // XCD-swizzled decode. blocks = NBT*sd*4; gid -> (xcd, k); 4 consecutive
    // k on one XCD share one (b,d) tile (different m) -> x-tile L2 reuse.
    const int gid  = blockIdx.x;
    const int xcd  = gid & 7;
    const int k    = gid >> 3;
    const int m_id = k & 3;
    const int tile = (k >> 2) * 8 + xcd;
    const int b_id = tile & (NBT - 1);
    const int d_id = tile / NBT;

    const int m0 = m_id * BM;
    const int b0 = b_id * BB;
    const int d0 = d_id * dc;
    const int NC = dc / KC;

    // staging source pointers (advance by KC per stage); all 16B-aligned
    const int rowx = tid >> 2, segx = tid & 3;
    const float* xp0 = x + (size_t)(b0 + rowx) * DD + d0 + segx * 4;
    const float* xp1 = xp0 + (size_t)64 * DD;
    const float* rp  = rbuf + (size_t)(m0 + rowx) * DD + d0 + segx * 4;

    float4 cx0 = *(const float4*)xp0;
    float4 cx1 = *(const float4*)xp1;
    float4 cr  = *(const float4*)rp;

    // prod2[i2][j] = {prod[2*i2][j], prod[2*i2+1][j]} — packed along batch
    v2f prod2[TB / 2][TM];
    int acce[TB][TM];
    #pragma unroll
    for (int i2 = 0; i2 < TB / 2; ++i2)
        #pragma unroll
        for (int j = 0; j < TM; ++j) prod2[i2][j] = (v2f){1.0f, 1.0f};
    #pragma unroll
    for (int i = 0; i < TB; ++i)
        #pragma unroll
        for (int j = 0; j < TM; ++j) acce[i][j] = 0;

    const v2f one2 = (v2f){1.0f, 1.0f};

    for (int c = 0; c < NC; ++c) {
        __syncthreads();
        // commit current staging registers to LDS (transposed, padded)
        {
            const int base = segx * 4;
            lx[(base + 0) * LXS + rowx] = cx0.x;
            lx[(base + 1) * LXS + rowx] = cx0.y;
            lx[(base + 2) * LXS + rowx] = cx0.z;
            lx[(base + 3) * LXS + rowx] = cx0.w;
            lx[(base + 0) * LXS + rowx + 64] = cx1.x;
            lx[(base + 1) * LXS + rowx + 64] = cx1.y;
            lx[(base + 2) * LXS + rowx + 64] = cx1.z;
            lx[(base + 3) * LXS + rowx + 64] = cx1.w;
            if (rowx < BM) {
                lr[(base + 0) * LRS + rowx] = cr.x;
                lr[(base + 1) * LRS + rowx] = cr.y;
                lr[(base + 2) * LRS + rowx] = cr.z;
                lr[(base + 3) * LRS + rowx] = cr.w;
            }
        }
        // prefetch next stage into registers (hides HBM latency behind compute)
        if (c + 1 < NC) {
            xp0 += KC; xp1 += KC; rp += KC;
            cx0 = *(const float4*)xp0;
            cx1 = *(const float4*)xp1;
            cr  = *(const float4*)rp;
        }
        __syncthreads();

        #pragma unroll
        for (int kc = 0; kc < KC; ++kc) {
            const float4* xp = (const float4*)&lx[kc * LXS + TB * ty];
            float4 xa = xp[0], xb = xp[1];
            const float4* rpf = (const float4*)&lr[kc * LRS + TM * tx];
            float4 rv = rpf[0];
            v2f xs[TB / 2] = {(v2f){xa.x, xa.y}, (v2f){xa.z, xa.w},
                              (v2f){xb.x, xb.y}, (v2f){xb.z, xb.w}};
            v2f rs[TM] = {(v2f){rv.x, rv.x}, (v2f){rv.y, rv.y},
                          (v2f){rv.z, rv.z}, (v2f){rv.w, rv.w}};
            #pragma unroll
            for (int i2 = 0; i2 < TB / 2; ++i2)
                #pragma unroll
                for (int j = 0; j < TM; ++j) {
                    v2f t = __builtin_elementwise_fma(xs[i2], rs[j], one2);
                    prod2[i2][j] = prod2[i2][j] * t;
                }
        }
        // close the 16-d stage: exact exponent extraction (range-safe, see
        // kernel comment: stage product bounded within fp32 normal range)
        #pragma unroll
        for (int i2 = 0; i2 < TB / 2; ++i2)
            #pragma unroll
            for (int j = 0; j < TM; ++j) {
                float p0 = prod2[i2][j].x, p1 = prod2[i2][j].y;
                acce[2 * i2 + 0][j] += fr_exp(p0);
                acce[2 * i2 + 1][j] += fr_exp(p1);
                prod2[i2][j] = (v2f){fr_mant(p0), fr_mant(p1)};
            }
    }

    // coalesced float4 stores: pbuf[d_id][b][m]
    float* pb = pbuf + ((size_t)d_id * BATCH + b0) * MM + m0;
    #pragma unroll
    for (int i = 0; i < TB; ++i) {
        const int i2 = i >> 1;
        float p0 = (i & 1) ? prod2[i2][0].y : prod2[i2][0].x;
        float p1 = (i & 1) ? prod2[i2][1].y : prod2[i2][1].x;
        float p2 = (i & 1) ? prod2[i2][2].y : prod2[i2][2].x;
        float p3 = (i & 1) ? prod2[i2][3].y : prod2[i2][3].x;
        float4 vv;
        vv.x = (float)acce[i][0] + __log2f(p0);
        vv.y = (float)acce[i][1] + __log2f(p1);
        vv.z = (float)acce[i][2] + __log2f(p2);
        vv.w = (float)acce[i][3] + __log2f(p3);
        *(float4*)&pb[(size_t)(TB * ty + i) * MM + TM * tx] = vv;
    }
}

// ---------------------------------------------------------------------------
// Kernel C (sd=16 fast path): one wave per batch, lane covers 4 m's (float4).
// 16 fully-unrolled independent dwordx4 loads -> MLP-saturated.
// ---------------------------------------------------------------------------
__global__ __launch_bounds__(256) void finalize16_kernel(
        const float4* __restrict__ pbuf4, const float4* __restrict__ cst4,
        float* __restrict__ out) {
    const int lane = threadIdx.x & 63;
    const int w = threadIdx.x >> 6;
    const int b = blockIdx.x * 4 + w;

    float4 v = cst4[lane];
    const float4* pb = pbuf4 + (size_t)b * (MM / 4) + lane;
    #pragma unroll
    for (int s = 0; s < 16; ++s) {
        float4 t = pb[(size_t)s * BATCH * (MM / 4)];
        v.x += t.x; v.y += t.y; v.z += t.z; v.w += t.w;
    }

    float mx = fmaxf(fmaxf(v.x, v.y), fmaxf(v.z, v.w));
    #pragma unroll
    for (int o = 32; o; o >>= 1) mx = fmaxf(mx, __shfl_xor(mx, o));

    float s = exp2f(v.x - mx) + exp2f(v.y - mx) + exp2f(v.z - mx) + exp2f(v.w - mx);
    #pragma unroll
    for (int o = 32; o; o >>= 1) s += __shfl_xor(s, o);

    if (lane == 0) out[b] = LN2 * (mx + __log2f(s));
}

// Generic fallback (sd != 16)
__global__ __launch_bounds__(256) void finalize_kernel(
        const float* __restrict__ pbuf, const float* __restrict__ cst,
        float* __restrict__ out, int sd) {
    const int lane = threadIdx.x & 63;
    const int w = threadIdx.x >> 6;
    const int b = blockIdx.x * 4 + w;

    float v0 = cst[lane];
    float v1 = cst[lane + 64];
    float v2 = cst[lane + 128];
    float v3 = cst[lane + 192];

    for (int s = 0; s < sd; ++s) {
        const float* row = pbuf + ((size_t)s * BATCH + b) * MM;
        v0 += row[lane];
        v1 += row[lane + 64];
        v2 += row[lane + 128];
        v3 += row[lane + 192];
    }

    float mx = fmaxf(fmaxf(v0, v1), fmaxf(v2, v3));
    #pragma unroll
    for (int o = 32; o; o >>= 1) mx = fmaxf(mx, __shfl_xor(mx, o));

    float s = exp2f(v0 - mx) + exp2f(v1 - mx) + exp2f(v2 - mx) + exp2f(v3 - mx);
    #pragma unroll
    for (int o = 32; o; o >>= 1) s += __shfl_xor(s, o);

    if (lane == 0) out[b] = LN2 * (mx + __log2f(s));
}

extern "C" void kernel_launch(void* const* d_in, const int* in_sizes, int n_in,
                              void* d_out, int out_size, void* d_ws, size_t ws_size,
                              hipStream_t stream) {
    const float* x  = (const float*)d_in[0];
    const float* Wv = (const float*)d_in[1];
    const float* P  = (const float*)d_in[2];

    // ws layout (floats): [rbuf: MM*DD][cst: MM][pbuf: sd*BATCH*MM]
    float* ws   = (float*)d_ws;
    float* rbuf = ws;
    float* cst  = rbuf + (size_t)MM * DD;
    float* pbuf = cst + MM;

    size_t fixed = ((size_t)MM * DD + MM) * sizeof(float);
    size_t avail = (ws_size > fixed) ? (ws_size - fixed) : 0;
    int sd = 16;
    while (sd > 1 && (size_t)sd * BATCH * MM * sizeof(float) > avail) sd >>= 1;

    precomp_kernel<<<MM, 256, 0, stream>>>(P, Wv, rbuf, cst);
    int nblocks = NBT * sd * 4;   // 1-D swizzled grid
    main_kernel<<<nblocks, 256, 0, stream>>>(x, rbuf, pbuf, DD / sd);
    if (sd == 16)
        finalize16_kernel<<<BATCH / 4, 256, 0, stream>>>(
            (const float4*)pbuf, (const float4*)cst, (float*)d_out);
    else
        finalize_kernel<<<BATCH / 4, 256, 0, stream>>>(pbuf, cst, (float*)d_out, sd);
}